// Round 5
// baseline (82.081 us; speedup 1.0000x reference)
//
#include <hip/hip_runtime.h>

typedef unsigned short u16;
typedef __attribute__((ext_vector_type(4))) float f32x4;
typedef __attribute__((ext_vector_type(8))) short bf16x8;
typedef __attribute__((ext_vector_type(4))) u16 u16x4;

#define MFMA(a, b, c) __builtin_amdgcn_mfma_f32_16x16x32_bf16(a, b, c, 0, 0, 0)

__device__ __forceinline__ u16 f2bf(float f) {
    unsigned u = __float_as_uint(f);
    u += 0x7fffu + ((u >> 16) & 1u);   // round-to-nearest-even
    return (u16)(u >> 16);
}

__device__ __forceinline__ void load_lds16(const void* g, void* l) {
    __builtin_amdgcn_global_load_lds((const __attribute__((address_space(1))) void*)g,
                                     (__attribute__((address_space(3))) void*)l,
                                     16, 0, 0);
}

// ---------------------------------------------------------------------------
// Kernel 1: pack Wq|Wk|Wv (fp32 [1024][64]) -> Wtt bf16, tile-major + swizzled:
// Wtt[kt][n][ (c ^ (n&7))*8 + ci ]. Stages linearly into LDS; baked XOR
// swizzle makes the B-frag ds_read_b128 conflict-free.
// ---------------------------------------------------------------------------
__global__ void wt_pack(const float* __restrict__ Wq, const float* __restrict__ Wk,
                        const float* __restrict__ Wv, u16* __restrict__ Wtt) {
    const int k = blockIdx.x;        // 0..1023
    const int n = threadIdx.x;       // 0..191
    const float* W = (n < 64) ? Wq : (n < 128 ? Wk : Wv);
    const float v = W[(size_t)k * 64 + (n & 63)];
    const int kt = k >> 6, ks = k & 63, c = ks >> 3, ci = ks & 7;
    Wtt[(size_t)kt * 12288 + n * 64 + (((c ^ (n & 7)) << 3) + ci)] = f2bf(v);
}

// ---------------------------------------------------------------------------
// Kernel 2: qkv projection, m97-structure (global_load_lds + 1 barrier/K-step).
// Q output is PRE-SCALED by log2(e)/sqrt(1024) so attention's exp2 needs no
// per-element scale.
// ---------------------------------------------------------------------------
__global__ __launch_bounds__(256, 2) void qkv_gemm(const float* __restrict__ x,
                                                   const u16* __restrict__ Wtt,
                                                   u16* __restrict__ qo,
                                                   u16* __restrict__ ko,
                                                   u16* __restrict__ vT) {
    const int tid = threadIdx.x;
    const int lane = tid & 63, wave = tid >> 6;
    const int lr = lane & 15, lg = lane >> 4;
    const int m0 = blockIdx.x * 32;

    __shared__ __align__(16) float xs[2][32 * 64];   // 8KB each
    __shared__ __align__(16) u16 ws[2][192 * 64];    // 24KB each

    f32x4 acc[2][3];
#pragma unroll
    for (int m = 0; m < 2; ++m)
#pragma unroll
        for (int n = 0; n < 3; ++n) acc[m][n] = (f32x4){0.f, 0.f, 0.f, 0.f};

    const int srow = tid >> 4;            // 0..15
    const int schk = tid & 15;            // x 16B-chunk within row

    {
#pragma unroll
        for (int j = 0; j < 2; ++j) {
            const int rr = j * 16 + srow;
            const float* src = x + (size_t)(m0 + rr) * 1024 + ((schk ^ (rr & 7)) << 2);
            load_lds16(src, &xs[0][j * 1024 + wave * 256]);
        }
#pragma unroll
        for (int j = 0; j < 6; ++j) {
            const u16* src = Wtt + (size_t)j * 2048 + tid * 8;
            load_lds16(src, &ws[0][j * 2048 + wave * 512]);
        }
    }
    __syncthreads();

    for (int kt = 0; kt < 16; ++kt) {
        const int cur = kt & 1;
        if (kt < 15) {
            const int nxt = cur ^ 1;
#pragma unroll
            for (int j = 0; j < 2; ++j) {
                const int rr = j * 16 + srow;
                const float* src =
                    x + (size_t)(m0 + rr) * 1024 + (kt + 1) * 64 + ((schk ^ (rr & 7)) << 2);
                load_lds16(src, &xs[nxt][j * 1024 + wave * 256]);
            }
#pragma unroll
            for (int j = 0; j < 6; ++j) {
                const u16* src = Wtt + (size_t)(kt + 1) * 12288 + j * 2048 + tid * 8;
                load_lds16(src, &ws[nxt][j * 2048 + wave * 512]);
            }
        }
#pragma unroll
        for (int h = 0; h < 2; ++h) {
            bf16x8 a[2];
#pragma unroll
            for (int mm = 0; mm < 2; ++mm) {
                const int rr = mm * 16 + lr;
                const int c0 = h * 8 + lg * 2;
                f32x4 f0 = *(const f32x4*)&xs[cur][rr * 64 + ((c0 ^ (rr & 7)) << 2)];
                f32x4 f1 = *(const f32x4*)&xs[cur][rr * 64 + (((c0 + 1) ^ (rr & 7)) << 2)];
                bf16x8 t;
#pragma unroll
                for (int i = 0; i < 4; ++i) {
                    t[i] = (short)f2bf(f0[i]);
                    t[i + 4] = (short)f2bf(f1[i]);
                }
                a[mm] = t;
            }
#pragma unroll
            for (int nl = 0; nl < 3; ++nl) {
                const int row = (wave * 3 + nl) * 16 + lr;
                const int cb = h * 4 + lg;
                const bf16x8 b = *(const bf16x8*)&ws[cur][row * 64 + ((cb ^ (row & 7)) << 3)];
                acc[0][nl] = MFMA(a[0], b, acc[0][nl]);
                acc[1][nl] = MFMA(a[1], b, acc[1][nl]);
            }
        }
        __syncthreads();
    }

    const float SCQ = 0.0450842200277801f;   // log2(e)/sqrt(1024)
    const int bb = m0 >> 11;
    const int tb = m0 & 2047;
#pragma unroll
    for (int mm = 0; mm < 2; ++mm)
#pragma unroll
        for (int nl = 0; nl < 3; ++nl) {
            const int col = (wave * 3 + nl) * 16 + lr;
            const int rl = mm * 16 + lg * 4;
            if (col < 64) {
#pragma unroll
                for (int r = 0; r < 4; ++r)
                    qo[(size_t)(m0 + rl + r) * 64 + col] = f2bf(acc[mm][nl][r] * SCQ);
            } else if (col < 128) {
#pragma unroll
                for (int r = 0; r < 4; ++r)
                    ko[(size_t)(m0 + rl + r) * 64 + (col - 64)] = f2bf(acc[mm][nl][r]);
            } else {
                u16x4 pk;
#pragma unroll
                for (int r = 0; r < 4; ++r) pk[r] = f2bf(acc[mm][nl][r]);
                *(u16x4*)&vT[(size_t)(bb * 64 + (col - 128)) * 2048 + tb + rl] = pk;
            }
        }
}

// ---------------------------------------------------------------------------
// Kernel 3: split-KV causal attention, fixed-max (m==0) softmax: p = exp2(s)
// directly (q pre-scaled). Zero shuffles / zero rescale in the kv loop;
// per-lane partial row-sums, one reduce at the end. Dense unit enumeration:
// wave u covers (b = blk&7, q-tile qt, 256-wide kv chunk c); 4608 active
// waves, no empty ones. Blocks share b -> XCD-local K/V in L2.
// ---------------------------------------------------------------------------
__global__ __launch_bounds__(256, 2) void attn_part(const u16* __restrict__ q,
                                                    const u16* __restrict__ k,
                                                    const u16* __restrict__ vT,
                                                    float* __restrict__ Op,
                                                    float* __restrict__ Lp) {
    const int b = blockIdx.x & 7;
    const int g = blockIdx.x >> 3;            // 0..143
    const int wave = threadIdx.x >> 6, lane = threadIdx.x & 63;
    const int t = 575 - (g * 4 + wave);       // dense unit id, heavy-first
    // decode t -> (c, qt): c-major blocks of size 128-16c
    int rem = t, c = 0;
    while (rem >= 128 - 16 * c) { rem -= 128 - 16 * c; ++c; }
    const int qt = 16 * c + rem;
    const int q0 = qt * 16;
    const int kv_lo = c * 256;
    const int kv_hi = min(kv_lo + 256, q0 + 16);
    const int slot = b * 576 + t;

    __shared__ __align__(16) u16 lP[4][16 * 72];   // per-wave P [16][72]

    const int lr = lane & 15, lg = lane >> 4;
    const u16* qb = q + (size_t)b * 2048 * 64;
    const u16* kb = k + (size_t)b * 2048 * 64;
    const u16* vb = vT + (size_t)b * 64 * 2048;

    const int qrow = q0 + lr;
    const bf16x8 qf0 = *(const bf16x8*)(qb + (size_t)qrow * 64 + lg * 8);
    const bf16x8 qf1 = *(const bf16x8*)(qb + (size_t)qrow * 64 + 32 + lg * 8);

    f32x4 oacc[4];
#pragma unroll
    for (int n = 0; n < 4; ++n) oacc[n] = (f32x4){0.f, 0.f, 0.f, 0.f};
    float rs[4] = {0.f, 0.f, 0.f, 0.f};
    const int row0 = q0 + lg * 4;             // lane's first q-row

    for (int kv0 = kv_lo; kv0 < kv_hi; kv0 += 64) {
        // ---- batched K + V loads (16 x 16B, all independent, in flight together)
        bf16x8 kf[4][2];
#pragma unroll
        for (int n = 0; n < 4; ++n) {
            const u16* kp = kb + (size_t)(kv0 + n * 16 + lr) * 64 + lg * 8;
            kf[n][0] = *(const bf16x8*)(kp);
            kf[n][1] = *(const bf16x8*)(kp + 32);
        }
        bf16x8 vf[2][4];
#pragma unroll
        for (int kc = 0; kc < 2; ++kc)
#pragma unroll
            for (int n = 0; n < 4; ++n)
                vf[kc][n] = *(const bf16x8*)(vb + (size_t)(n * 16 + lr) * 2048 + kv0 +
                                             kc * 32 + lg * 8);

        // ---- S = Q K^T (already in log2-softmax domain)
        f32x4 s[4];
#pragma unroll
        for (int n = 0; n < 4; ++n) {
            f32x4 a = (f32x4){0.f, 0.f, 0.f, 0.f};
            a = MFMA(qf0, kf[n][0], a);
            a = MFMA(qf1, kf[n][1], a);
            s[n] = a;
        }

        // ---- p = exp2(s) (+ causal zeroing on diagonal tiles); accumulate rs
        if (kv0 + 63 > q0) {
#pragma unroll
            for (int n = 0; n < 4; ++n) {
                const int col = kv0 + n * 16 + lr;
#pragma unroll
                for (int r = 0; r < 4; ++r) {
                    float p = (col <= row0 + r) ? exp2f(s[n][r]) : 0.f;
                    rs[r] += p;
                    lP[wave][(lg * 4 + r) * 72 + n * 16 + lr] = f2bf(p);
                }
            }
        } else {
#pragma unroll
            for (int n = 0; n < 4; ++n)
#pragma unroll
                for (int r = 0; r < 4; ++r) {
                    float p = exp2f(s[n][r]);
                    rs[r] += p;
                    lP[wave][(lg * 4 + r) * 72 + n * 16 + lr] = f2bf(p);
                }
        }

        // ---- PV
#pragma unroll
        for (int kc = 0; kc < 2; ++kc) {
            const bf16x8 pf = *(const bf16x8*)&lP[wave][lr * 72 + kc * 32 + lg * 8];
#pragma unroll
            for (int n = 0; n < 4; ++n) oacc[n] = MFMA(pf, vf[kc][n], oacc[n]);
        }
    }

    // ---- end-of-chunk row-sum reduce (only place with shuffles)
#pragma unroll
    for (int d = 1; d < 16; d <<= 1)
#pragma unroll
        for (int r = 0; r < 4; ++r) rs[r] += __shfl_xor(rs[r], d);

    float* op = Op + (size_t)slot * 1024;
#pragma unroll
    for (int r = 0; r < 4; ++r) {
#pragma unroll
        for (int n = 0; n < 4; ++n) op[(lg * 4 + r) * 64 + n * 16 + lr] = oacc[n][r];
        if (lr == 0) Lp[slot * 16 + lg * 4 + r] = rs[r];
    }
}

// ---------------------------------------------------------------------------
// Kernel 4: merge <=8 kv-chunk partials (plain sums; fixed max) + normalize.
// ---------------------------------------------------------------------------
__global__ __launch_bounds__(256) void attn_combine(const float* __restrict__ Op,
                                                    const float* __restrict__ Lp,
                                                    float* __restrict__ out) {
    const int gid = blockIdx.x * 256 + threadIdx.x;   // 1048576
    const int col = gid & 63;
    const int row = gid >> 6;            // b*2048 + t
    const int b = row >> 11, tt = row & 2047;
    const int qt = tt >> 4, i = tt & 15;
    const int nc = (qt >> 4) + 1;

    float O = 0.f, L = 0.f;
    int base = 0;
    for (int c = 0; c < nc; ++c) {
        const int slot = b * 576 + base + (qt - 16 * c);
        O += Op[(size_t)slot * 1024 + i * 64 + col];
        L += Lp[slot * 16 + i];
        base += 128 - 16 * c;
    }
    out[(size_t)row * 64 + col] = O / L;
}

// ---------------------------------------------------------------------------
extern "C" void kernel_launch(void* const* d_in, const int* in_sizes, int n_in,
                              void* d_out, int out_size, void* d_ws, size_t ws_size,
                              hipStream_t stream) {
    const float* x = (const float*)d_in[0];
    const float* Wq = (const float*)d_in[1];
    const float* Wk = (const float*)d_in[2];
    const float* Wv = (const float*)d_in[3];
    float* out = (float*)d_out;

    char* ws = (char*)d_ws;
    u16* Wtt = (u16*)ws;                                  // 384 KB @ 0
    u16* qb = (u16*)(ws + (512 << 10));                   // 2 MB
    u16* kb = (u16*)(ws + (512 << 10) + (2 << 20));       // 2 MB
    u16* vT = (u16*)(ws + (512 << 10) + (4 << 20));       // 2 MB
    float* Op = (float*)(ws + (8 << 20));                 // 4608*1024*4 = 18.9 MB
    float* Lp = (float*)(ws + (27 << 20));                // 4608*16*4 = 288 KB

    wt_pack<<<1024, 192, 0, stream>>>(Wq, Wk, Wv, Wtt);
    qkv_gemm<<<512, 256, 0, stream>>>(x, Wtt, qb, kb, vT);
    attn_part<<<1152, 256, 0, stream>>>(qb, kb, vT, Op, Lp);
    attn_combine<<<4096, 256, 0, stream>>>(Op, Lp, out);
}

// Round 6
// 57.206 us; speedup vs baseline: 1.4348x; 1.4348x over previous
//
#include <hip/hip_runtime.h>

typedef unsigned short u16;
typedef __attribute__((ext_vector_type(4))) float f32x4;
typedef __attribute__((ext_vector_type(8))) short bf16x8;
typedef __attribute__((ext_vector_type(4))) u16 u16x4;

#define MFMA(a, b, c) __builtin_amdgcn_mfma_f32_16x16x32_bf16(a, b, c, 0, 0, 0)

__device__ __forceinline__ u16 f2bf(float f) {
    unsigned u = __float_as_uint(f);
    u += 0x7fffu + ((u >> 16) & 1u);   // round-to-nearest-even
    return (u16)(u >> 16);
}

__device__ __forceinline__ void load_lds16(const void* g, void* l) {
    __builtin_amdgcn_global_load_lds((const __attribute__((address_space(1))) void*)g,
                                     (__attribute__((address_space(3))) void*)l,
                                     16, 0, 0);
}

// ---------------------------------------------------------------------------
// Kernel 1: pack Wq|Wk|Wv (fp32 [1024][64]) -> Wtt bf16, tile-major + swizzled.
// ---------------------------------------------------------------------------
__global__ void wt_pack(const float* __restrict__ Wq, const float* __restrict__ Wk,
                        const float* __restrict__ Wv, u16* __restrict__ Wtt) {
    const int k = blockIdx.x;        // 0..1023
    const int n = threadIdx.x;       // 0..191
    const float* W = (n < 64) ? Wq : (n < 128 ? Wk : Wv);
    const float v = W[(size_t)k * 64 + (n & 63)];
    const int kt = k >> 6, ks = k & 63, c = ks >> 3, ci = ks & 7;
    Wtt[(size_t)kt * 12288 + n * 64 + (((c ^ (n & 7)) << 3) + ci)] = f2bf(v);
}

// ---------------------------------------------------------------------------
// Kernel 2: qkv projection, m97-structure (unchanged from R5; ~15us).
// Q output pre-scaled by log2(e)/sqrt(1024).
// ---------------------------------------------------------------------------
__global__ __launch_bounds__(256, 2) void qkv_gemm(const float* __restrict__ x,
                                                   const u16* __restrict__ Wtt,
                                                   u16* __restrict__ qo,
                                                   u16* __restrict__ ko,
                                                   u16* __restrict__ vT) {
    const int tid = threadIdx.x;
    const int lane = tid & 63, wave = tid >> 6;
    const int lr = lane & 15, lg = lane >> 4;
    const int m0 = blockIdx.x * 32;

    __shared__ __align__(16) float xs[2][32 * 64];
    __shared__ __align__(16) u16 ws[2][192 * 64];

    f32x4 acc[2][3];
#pragma unroll
    for (int m = 0; m < 2; ++m)
#pragma unroll
        for (int n = 0; n < 3; ++n) acc[m][n] = (f32x4){0.f, 0.f, 0.f, 0.f};

    const int srow = tid >> 4;
    const int schk = tid & 15;

    {
#pragma unroll
        for (int j = 0; j < 2; ++j) {
            const int rr = j * 16 + srow;
            const float* src = x + (size_t)(m0 + rr) * 1024 + ((schk ^ (rr & 7)) << 2);
            load_lds16(src, &xs[0][j * 1024 + wave * 256]);
        }
#pragma unroll
        for (int j = 0; j < 6; ++j) {
            const u16* src = Wtt + (size_t)j * 2048 + tid * 8;
            load_lds16(src, &ws[0][j * 2048 + wave * 512]);
        }
    }
    __syncthreads();

    for (int kt = 0; kt < 16; ++kt) {
        const int cur = kt & 1;
        if (kt < 15) {
            const int nxt = cur ^ 1;
#pragma unroll
            for (int j = 0; j < 2; ++j) {
                const int rr = j * 16 + srow;
                const float* src =
                    x + (size_t)(m0 + rr) * 1024 + (kt + 1) * 64 + ((schk ^ (rr & 7)) << 2);
                load_lds16(src, &xs[nxt][j * 1024 + wave * 256]);
            }
#pragma unroll
            for (int j = 0; j < 6; ++j) {
                const u16* src = Wtt + (size_t)(kt + 1) * 12288 + j * 2048 + tid * 8;
                load_lds16(src, &ws[nxt][j * 2048 + wave * 512]);
            }
        }
#pragma unroll
        for (int h = 0; h < 2; ++h) {
            bf16x8 a[2];
#pragma unroll
            for (int mm = 0; mm < 2; ++mm) {
                const int rr = mm * 16 + lr;
                const int c0 = h * 8 + lg * 2;
                f32x4 f0 = *(const f32x4*)&xs[cur][rr * 64 + ((c0 ^ (rr & 7)) << 2)];
                f32x4 f1 = *(const f32x4*)&xs[cur][rr * 64 + (((c0 + 1) ^ (rr & 7)) << 2)];
                bf16x8 t;
#pragma unroll
                for (int i = 0; i < 4; ++i) {
                    t[i] = (short)f2bf(f0[i]);
                    t[i + 4] = (short)f2bf(f1[i]);
                }
                a[mm] = t;
            }
#pragma unroll
            for (int nl = 0; nl < 3; ++nl) {
                const int row = (wave * 3 + nl) * 16 + lr;
                const int cb = h * 4 + lg;
                const bf16x8 b = *(const bf16x8*)&ws[cur][row * 64 + ((cb ^ (row & 7)) << 3)];
                acc[0][nl] = MFMA(a[0], b, acc[0][nl]);
                acc[1][nl] = MFMA(a[1], b, acc[1][nl]);
            }
        }
        __syncthreads();
    }

    const float SCQ = 0.0450842200277801f;   // log2(e)/sqrt(1024)
    const int bb = m0 >> 11;
    const int tb = m0 & 2047;
#pragma unroll
    for (int mm = 0; mm < 2; ++mm)
#pragma unroll
        for (int nl = 0; nl < 3; ++nl) {
            const int col = (wave * 3 + nl) * 16 + lr;
            const int rl = mm * 16 + lg * 4;
            if (col < 64) {
#pragma unroll
                for (int r = 0; r < 4; ++r)
                    qo[(size_t)(m0 + rl + r) * 64 + col] = f2bf(acc[mm][nl][r] * SCQ);
            } else if (col < 128) {
#pragma unroll
                for (int r = 0; r < 4; ++r)
                    ko[(size_t)(m0 + rl + r) * 64 + (col - 64)] = f2bf(acc[mm][nl][r]);
            } else {
                u16x4 pk;
#pragma unroll
                for (int r = 0; r < 4; ++r) pk[r] = f2bf(acc[mm][nl][r]);
                *(u16x4*)&vT[(size_t)(bb * 64 + (col - 128)) * 2048 + tb + rl] = pk;
            }
        }
}

// ---------------------------------------------------------------------------
// Kernel 3: causal attention, LDS-staged (2-phase global_load_lds template).
// Block = 4 waves = (b, 64 q-rows, <=512 kv chunk); wave w owns rows
// q0+16w..+15. K/V 64x64-bf16 tiles double-buffered in LDS (XOR-swizzled
// global source, linear dest; reads 2-way free). Swapped QK^T (S^T) makes
// P kv-contiguous per lane: 4x ds_write_b64 + 2-shfl rowsum. Fixed-max
// softmax: p = exp2(s) (q pre-scaled).
// ---------------------------------------------------------------------------
#define PPITCH 72
__global__ __launch_bounds__(256, 2) void attn_part(const u16* __restrict__ q,
                                                    const u16* __restrict__ k,
                                                    const u16* __restrict__ vT,
                                                    float* __restrict__ Op,
                                                    float* __restrict__ Lp) {
    const int b = blockIdx.x & 7;
    int g = blockIdx.x >> 3;                  // 0..79, heavy-first
    int qt = 31, rem = g;
    while (rem >= (qt >> 3) + 1) { rem -= (qt >> 3) + 1; --qt; }
    const int c0 = rem;
    const int q0 = qt * 64;
    const int kv_lo = c0 * 512;
    const int kv_hi = min(kv_lo + 512, q0 + 64);
    const int ntiles = (kv_hi - kv_lo) >> 6;
    const int slot = (b * 32 + qt) * 4 + c0;

    __shared__ __align__(16) u16 lK[2][64 * 64];     // 8KB each
    __shared__ __align__(16) u16 lV[2][64 * 64];     // 8KB each
    __shared__ __align__(16) u16 lP[4][16 * PPITCH]; // per-wave P

    const int tid = threadIdx.x;
    const int wave = tid >> 6, lane = tid & 63;
    const int lr = lane & 15, lg = lane >> 4;

    const u16* qb = q + (size_t)b * 2048 * 64;
    const u16* kb = k + (size_t)b * 2048 * 64;
    const u16* vb = vT + (size_t)b * 64 * 2048;

    // wave's 16 q-rows in registers
    const int myrow = q0 + wave * 16 + lr;
    const bf16x8 qf0 = *(const bf16x8*)(qb + (size_t)myrow * 64 + lg * 8);
    const bf16x8 qf1 = *(const bf16x8*)(qb + (size_t)myrow * 64 + 32 + lg * 8);

    f32x4 oacc[4];
#pragma unroll
    for (int n = 0; n < 4; ++n) oacc[n] = (f32x4){0.f, 0.f, 0.f, 0.f};
    float rs = 0.f;

    // ---- staging helper geometry: 512 16B-chunks per tile, 2 per thread
    // chunk id = j*256 + wave*64 + lane; row = cid>>3, c = cid&7;
    // global src col-chunk = c ^ (row&7); LDS dest linear (wave-uniform base).
#define STAGE(bufi, kv0_)                                                             \
    {                                                                                 \
        _Pragma("unroll") for (int j = 0; j < 2; ++j) {                               \
            const int cid = j * 256 + wave * 64 + lane;                               \
            const int row = cid >> 3, cc = cid & 7;                                   \
            load_lds16(kb + (size_t)((kv0_) + row) * 64 + ((cc ^ (row & 7)) << 3),    \
                       &lK[bufi][(j * 256 + wave * 64) * 8]);                         \
            load_lds16(vb + (size_t)row * 2048 + (kv0_) + ((cc ^ (row & 7)) << 3),    \
                       &lV[bufi][(j * 256 + wave * 64) * 8]);                         \
        }                                                                             \
    }

    STAGE(0, kv_lo);
    __syncthreads();

    for (int it = 0; it < ntiles; ++it) {
        const int cur = it & 1;
        if (it + 1 < ntiles) STAGE(cur ^ 1, kv_lo + (it + 1) * 64);

        const int kv0 = kv_lo + it * 64;
        if (kv0 <= q0 + wave * 16 + 15) {      // wave-uniform causal guard
            // ---- K frags from LDS (swizzled), S^T = K . Q^T
            f32x4 s[4];
#pragma unroll
            for (int n = 0; n < 4; ++n) {
                const int row = n * 16 + lr;
                const bf16x8 kf0 = *(const bf16x8*)&lK[cur][row * 64 + ((lg ^ (row & 7)) << 3)];
                const bf16x8 kf1 =
                    *(const bf16x8*)&lK[cur][row * 64 + (((4 + lg) ^ (row & 7)) << 3)];
                f32x4 a = (f32x4){0.f, 0.f, 0.f, 0.f};
                a = MFMA(kf0, qf0, a);
                a = MFMA(kf1, qf1, a);
                s[n] = a;   // S^T: rows kv = 16n+lg*4+r, col q = lr
            }

            // ---- p = exp2(s), causal zero, P store (kv-contiguous b64 writes)
            const bool msk = (kv0 + 63 > q0 + wave * 16);
#pragma unroll
            for (int n = 0; n < 4; ++n) {
                u16x4 pk;
#pragma unroll
                for (int r = 0; r < 4; ++r) {
                    const int kvi = kv0 + n * 16 + lg * 4 + r;
                    const float p = (!msk || kvi <= myrow) ? exp2f(s[n][r]) : 0.f;
                    rs += p;
                    pk[r] = f2bf(p);
                }
                *(u16x4*)&lP[wave][lr * PPITCH + n * 16 + lg * 4] = pk;
            }

            // ---- PV: A = P (rows q), B = V^T rows h (swizzled LDS reads)
#pragma unroll
            for (int kc = 0; kc < 2; ++kc) {
                const bf16x8 pf = *(const bf16x8*)&lP[wave][lr * PPITCH + kc * 32 + lg * 8];
#pragma unroll
                for (int n = 0; n < 4; ++n) {
                    const int row = n * 16 + lr;
                    const bf16x8 vf =
                        *(const bf16x8*)&lV[cur][row * 64 + (((kc * 4 + lg) ^ (row & 7)) << 3)];
                    oacc[n] = MFMA(pf, vf, oacc[n]);
                }
            }
        }
        __syncthreads();
    }

    // ---- row-sum: combine the 4 lanes sharing lr
    rs += __shfl_xor(rs, 16);
    rs += __shfl_xor(rs, 32);
    if (lane < 16) Lp[slot * 64 + wave * 16 + lr] = rs;

    float* op = Op + (size_t)slot * 4096;
#pragma unroll
    for (int n = 0; n < 4; ++n)
#pragma unroll
        for (int r = 0; r < 4; ++r)
            op[(wave * 16 + lg * 4 + r) * 64 + n * 16 + lr] = oacc[n][r];
}

// ---------------------------------------------------------------------------
// Kernel 4: merge <=4 kv-chunk partials (plain sums; fixed max) + normalize.
// ---------------------------------------------------------------------------
__global__ __launch_bounds__(256) void attn_combine(const float* __restrict__ Op,
                                                    const float* __restrict__ Lp,
                                                    float* __restrict__ out) {
    const int gid = blockIdx.x * 256 + threadIdx.x;   // 1048576
    const int col = gid & 63;
    const int row = gid >> 6;            // b*2048 + t
    const int b = row >> 11, tt = row & 2047;
    const int qt = tt >> 6, i = tt & 63;
    const int nc = (qt >> 3) + 1;
    const size_t sbase = (size_t)(b * 32 + qt) * 4;

    float O = 0.f, L = 0.f;
    for (int c = 0; c < nc; ++c) {
        O += Op[(sbase + c) * 4096 + i * 64 + col];
        L += Lp[(sbase + c) * 64 + i];
    }
    out[(size_t)row * 64 + col] = O / L;
}

// ---------------------------------------------------------------------------
extern "C" void kernel_launch(void* const* d_in, const int* in_sizes, int n_in,
                              void* d_out, int out_size, void* d_ws, size_t ws_size,
                              hipStream_t stream) {
    const float* x = (const float*)d_in[0];
    const float* Wq = (const float*)d_in[1];
    const float* Wk = (const float*)d_in[2];
    const float* Wv = (const float*)d_in[3];
    float* out = (float*)d_out;

    char* ws = (char*)d_ws;
    u16* Wtt = (u16*)ws;                                  // 384 KB @ 0
    u16* qb = (u16*)(ws + (512 << 10));                   // 2 MB
    u16* kb = (u16*)(ws + (512 << 10) + (2 << 20));       // 2 MB
    u16* vT = (u16*)(ws + (512 << 10) + (4 << 20));       // 2 MB
    float* Op = (float*)(ws + (8 << 20));                 // 1024*4096*4 = 16.8 MB
    float* Lp = (float*)(ws + (25 << 20));                // 1024*64*4 = 256 KB

    wt_pack<<<1024, 192, 0, stream>>>(Wq, Wk, Wv, Wtt);
    qkv_gemm<<<512, 256, 0, stream>>>(x, Wtt, qb, kb, vT);
    attn_part<<<640, 256, 0, stream>>>(qb, kb, vT, Op, Lp);
    attn_combine<<<4096, 256, 0, stream>>>(Op, Lp, out);
}

// Round 7
// 57.127 us; speedup vs baseline: 1.4368x; 1.0014x over previous
//
#include <hip/hip_runtime.h>

typedef unsigned short u16;
typedef __attribute__((ext_vector_type(4))) float f32x4;
typedef __attribute__((ext_vector_type(8))) short bf16x8;
typedef __attribute__((ext_vector_type(4))) u16 u16x4;

#define MFMA(a, b, c) __builtin_amdgcn_mfma_f32_16x16x32_bf16(a, b, c, 0, 0, 0)

__device__ __forceinline__ u16 f2bf(float f) {
    unsigned u = __float_as_uint(f);
    u += 0x7fffu + ((u >> 16) & 1u);   // round-to-nearest-even
    return (u16)(u >> 16);
}

__device__ __forceinline__ void load_lds16(const void* g, void* l) {
    __builtin_amdgcn_global_load_lds((const __attribute__((address_space(1))) void*)g,
                                     (__attribute__((address_space(3))) void*)l,
                                     16, 0, 0);
}

// ---------------------------------------------------------------------------
// Kernel 1: pack Wq|Wk|Wv (fp32 [1024][64]) -> Wtt bf16, tile-major + swizzled.
// ---------------------------------------------------------------------------
__global__ void wt_pack(const float* __restrict__ Wq, const float* __restrict__ Wk,
                        const float* __restrict__ Wv, u16* __restrict__ Wtt) {
    const int k = blockIdx.x;        // 0..1023
    const int n = threadIdx.x;       // 0..191
    const float* W = (n < 64) ? Wq : (n < 128 ? Wk : Wv);
    const float v = W[(size_t)k * 64 + (n & 63)];
    const int kt = k >> 6, ks = k & 63, c = ks >> 3, ci = ks & 7;
    Wtt[(size_t)kt * 12288 + n * 64 + (((c ^ (n & 7)) << 3) + ci)] = f2bf(v);
}

// ---------------------------------------------------------------------------
// Kernel 2: qkv projection, m97-structure (unchanged; ~15us).
// Q output pre-scaled by log2(e)/sqrt(1024).
// ---------------------------------------------------------------------------
__global__ __launch_bounds__(256, 2) void qkv_gemm(const float* __restrict__ x,
                                                   const u16* __restrict__ Wtt,
                                                   u16* __restrict__ qo,
                                                   u16* __restrict__ ko,
                                                   u16* __restrict__ vT) {
    const int tid = threadIdx.x;
    const int lane = tid & 63, wave = tid >> 6;
    const int lr = lane & 15, lg = lane >> 4;
    const int m0 = blockIdx.x * 32;

    __shared__ __align__(16) float xs[2][32 * 64];
    __shared__ __align__(16) u16 ws[2][192 * 64];

    f32x4 acc[2][3];
#pragma unroll
    for (int m = 0; m < 2; ++m)
#pragma unroll
        for (int n = 0; n < 3; ++n) acc[m][n] = (f32x4){0.f, 0.f, 0.f, 0.f};

    const int srow = tid >> 4;
    const int schk = tid & 15;

    {
#pragma unroll
        for (int j = 0; j < 2; ++j) {
            const int rr = j * 16 + srow;
            const float* src = x + (size_t)(m0 + rr) * 1024 + ((schk ^ (rr & 7)) << 2);
            load_lds16(src, &xs[0][j * 1024 + wave * 256]);
        }
#pragma unroll
        for (int j = 0; j < 6; ++j) {
            const u16* src = Wtt + (size_t)j * 2048 + tid * 8;
            load_lds16(src, &ws[0][j * 2048 + wave * 512]);
        }
    }
    __syncthreads();

    for (int kt = 0; kt < 16; ++kt) {
        const int cur = kt & 1;
        if (kt < 15) {
            const int nxt = cur ^ 1;
#pragma unroll
            for (int j = 0; j < 2; ++j) {
                const int rr = j * 16 + srow;
                const float* src =
                    x + (size_t)(m0 + rr) * 1024 + (kt + 1) * 64 + ((schk ^ (rr & 7)) << 2);
                load_lds16(src, &xs[nxt][j * 1024 + wave * 256]);
            }
#pragma unroll
            for (int j = 0; j < 6; ++j) {
                const u16* src = Wtt + (size_t)(kt + 1) * 12288 + j * 2048 + tid * 8;
                load_lds16(src, &ws[nxt][j * 2048 + wave * 512]);
            }
        }
#pragma unroll
        for (int h = 0; h < 2; ++h) {
            bf16x8 a[2];
#pragma unroll
            for (int mm = 0; mm < 2; ++mm) {
                const int rr = mm * 16 + lr;
                const int c0 = h * 8 + lg * 2;
                f32x4 f0 = *(const f32x4*)&xs[cur][rr * 64 + ((c0 ^ (rr & 7)) << 2)];
                f32x4 f1 = *(const f32x4*)&xs[cur][rr * 64 + (((c0 + 1) ^ (rr & 7)) << 2)];
                bf16x8 t;
#pragma unroll
                for (int i = 0; i < 4; ++i) {
                    t[i] = (short)f2bf(f0[i]);
                    t[i + 4] = (short)f2bf(f1[i]);
                }
                a[mm] = t;
            }
#pragma unroll
            for (int nl = 0; nl < 3; ++nl) {
                const int row = (wave * 3 + nl) * 16 + lr;
                const int cb = h * 4 + lg;
                const bf16x8 b = *(const bf16x8*)&ws[cur][row * 64 + ((cb ^ (row & 7)) << 3)];
                acc[0][nl] = MFMA(a[0], b, acc[0][nl]);
                acc[1][nl] = MFMA(a[1], b, acc[1][nl]);
            }
        }
        __syncthreads();
    }

    const float SCQ = 0.0450842200277801f;   // log2(e)/sqrt(1024)
    const int bb = m0 >> 11;
    const int tb = m0 & 2047;
#pragma unroll
    for (int mm = 0; mm < 2; ++mm)
#pragma unroll
        for (int nl = 0; nl < 3; ++nl) {
            const int col = (wave * 3 + nl) * 16 + lr;
            const int rl = mm * 16 + lg * 4;
            if (col < 64) {
#pragma unroll
                for (int r = 0; r < 4; ++r)
                    qo[(size_t)(m0 + rl + r) * 64 + col] = f2bf(acc[mm][nl][r] * SCQ);
            } else if (col < 128) {
#pragma unroll
                for (int r = 0; r < 4; ++r)
                    ko[(size_t)(m0 + rl + r) * 64 + (col - 64)] = f2bf(acc[mm][nl][r]);
            } else {
                u16x4 pk;
#pragma unroll
                for (int r = 0; r < 4; ++r) pk[r] = f2bf(acc[mm][nl][r]);
                *(u16x4*)&vT[(size_t)(bb * 64 + (col - 128)) * 2048 + tb + rl] = pk;
            }
        }
}

// ---------------------------------------------------------------------------
// Kernel 3: causal attention, 2-phase global_load_lds template (as R6) but
// 3 blocks/CU: entire 640-block grid co-resident (768 slots), 12 waves/CU.
// LDS 41.2KB x 3 = 123.6KB < 160KB.
// ---------------------------------------------------------------------------
#define PPITCH 72
__global__ __launch_bounds__(256, 3) void attn_part(const u16* __restrict__ q,
                                                    const u16* __restrict__ k,
                                                    const u16* __restrict__ vT,
                                                    float* __restrict__ Op,
                                                    float* __restrict__ Lp) {
    const int b = blockIdx.x & 7;
    int g = blockIdx.x >> 3;                  // 0..79, heavy-first
    int qt = 31, rem = g;
    while (rem >= (qt >> 3) + 1) { rem -= (qt >> 3) + 1; --qt; }
    const int c0 = rem;
    const int q0 = qt * 64;
    const int kv_lo = c0 * 512;
    const int kv_hi = min(kv_lo + 512, q0 + 64);
    const int ntiles = (kv_hi - kv_lo) >> 6;
    const int slot = (b * 32 + qt) * 4 + c0;

    __shared__ __align__(16) u16 lK[2][64 * 64];     // 8KB each
    __shared__ __align__(16) u16 lV[2][64 * 64];     // 8KB each
    __shared__ __align__(16) u16 lP[4][16 * PPITCH]; // per-wave P

    const int tid = threadIdx.x;
    const int wave = tid >> 6, lane = tid & 63;
    const int lr = lane & 15, lg = lane >> 4;

    const u16* qb = q + (size_t)b * 2048 * 64;
    const u16* kb = k + (size_t)b * 2048 * 64;
    const u16* vb = vT + (size_t)b * 64 * 2048;

    // wave's 16 q-rows in registers
    const int myrow = q0 + wave * 16 + lr;
    const bf16x8 qf0 = *(const bf16x8*)(qb + (size_t)myrow * 64 + lg * 8);
    const bf16x8 qf1 = *(const bf16x8*)(qb + (size_t)myrow * 64 + 32 + lg * 8);

    f32x4 oacc[4];
#pragma unroll
    for (int n = 0; n < 4; ++n) oacc[n] = (f32x4){0.f, 0.f, 0.f, 0.f};
    float rs = 0.f;

#define STAGE(bufi, kv0_)                                                             \
    {                                                                                 \
        _Pragma("unroll") for (int j = 0; j < 2; ++j) {                               \
            const int cid = j * 256 + wave * 64 + lane;                               \
            const int row = cid >> 3, cc = cid & 7;                                   \
            load_lds16(kb + (size_t)((kv0_) + row) * 64 + ((cc ^ (row & 7)) << 3),    \
                       &lK[bufi][(j * 256 + wave * 64) * 8]);                         \
            load_lds16(vb + (size_t)row * 2048 + (kv0_) + ((cc ^ (row & 7)) << 3),    \
                       &lV[bufi][(j * 256 + wave * 64) * 8]);                         \
        }                                                                             \
    }

    STAGE(0, kv_lo);
    __syncthreads();

    for (int it = 0; it < ntiles; ++it) {
        const int cur = it & 1;
        if (it + 1 < ntiles) STAGE(cur ^ 1, kv_lo + (it + 1) * 64);

        const int kv0 = kv_lo + it * 64;
        if (kv0 <= q0 + wave * 16 + 15) {      // wave-uniform causal guard
            // ---- K frags from LDS (swizzled), S^T = K . Q^T
            f32x4 s[4];
#pragma unroll
            for (int n = 0; n < 4; ++n) {
                const int row = n * 16 + lr;
                const bf16x8 kf0 = *(const bf16x8*)&lK[cur][row * 64 + ((lg ^ (row & 7)) << 3)];
                const bf16x8 kf1 =
                    *(const bf16x8*)&lK[cur][row * 64 + (((4 + lg) ^ (row & 7)) << 3)];
                f32x4 a = (f32x4){0.f, 0.f, 0.f, 0.f};
                a = MFMA(kf0, qf0, a);
                a = MFMA(kf1, qf1, a);
                s[n] = a;   // S^T: rows kv = 16n+lg*4+r, col q = lr
            }

            // ---- p = exp2(s), causal zero, P store (kv-contiguous b64 writes)
            const bool msk = (kv0 + 63 > q0 + wave * 16);
#pragma unroll
            for (int n = 0; n < 4; ++n) {
                u16x4 pk;
#pragma unroll
                for (int r = 0; r < 4; ++r) {
                    const int kvi = kv0 + n * 16 + lg * 4 + r;
                    const float p = (!msk || kvi <= myrow) ? exp2f(s[n][r]) : 0.f;
                    rs += p;
                    pk[r] = f2bf(p);
                }
                *(u16x4*)&lP[wave][lr * PPITCH + n * 16 + lg * 4] = pk;
            }

            // ---- PV: A = P (rows q), B = V^T rows h (swizzled LDS reads)
#pragma unroll
            for (int kc = 0; kc < 2; ++kc) {
                const bf16x8 pf = *(const bf16x8*)&lP[wave][lr * PPITCH + kc * 32 + lg * 8];
#pragma unroll
                for (int n = 0; n < 4; ++n) {
                    const int row = n * 16 + lr;
                    const bf16x8 vf =
                        *(const bf16x8*)&lV[cur][row * 64 + (((kc * 4 + lg) ^ (row & 7)) << 3)];
                    oacc[n] = MFMA(pf, vf, oacc[n]);
                }
            }
        }
        __syncthreads();
    }

    // ---- row-sum: combine the 4 lanes sharing lr
    rs += __shfl_xor(rs, 16);
    rs += __shfl_xor(rs, 32);
    if (lane < 16) Lp[slot * 64 + wave * 16 + lr] = rs;

    float* op = Op + (size_t)slot * 4096;
#pragma unroll
    for (int n = 0; n < 4; ++n)
#pragma unroll
        for (int r = 0; r < 4; ++r)
            op[(wave * 16 + lg * 4 + r) * 64 + n * 16 + lr] = oacc[n][r];
}

// ---------------------------------------------------------------------------
// Kernel 4: merge <=4 kv-chunk partials (plain sums; fixed max) + normalize.
// ---------------------------------------------------------------------------
__global__ __launch_bounds__(256) void attn_combine(const float* __restrict__ Op,
                                                    const float* __restrict__ Lp,
                                                    float* __restrict__ out) {
    const int gid = blockIdx.x * 256 + threadIdx.x;   // 1048576
    const int col = gid & 63;
    const int row = gid >> 6;            // b*2048 + t
    const int b = row >> 11, tt = row & 2047;
    const int qt = tt >> 6, i = tt & 63;
    const int nc = (qt >> 3) + 1;
    const size_t sbase = (size_t)(b * 32 + qt) * 4;

    float O = 0.f, L = 0.f;
    for (int c = 0; c < nc; ++c) {
        O += Op[(sbase + c) * 4096 + i * 64 + col];
        L += Lp[(sbase + c) * 64 + i];
    }
    out[(size_t)row * 64 + col] = O / L;
}

// ---------------------------------------------------------------------------
extern "C" void kernel_launch(void* const* d_in, const int* in_sizes, int n_in,
                              void* d_out, int out_size, void* d_ws, size_t ws_size,
                              hipStream_t stream) {
    const float* x = (const float*)d_in[0];
    const float* Wq = (const float*)d_in[1];
    const float* Wk = (const float*)d_in[2];
    const float* Wv = (const float*)d_in[3];
    float* out = (float*)d_out;

    char* ws = (char*)d_ws;
    u16* Wtt = (u16*)ws;                                  // 384 KB @ 0
    u16* qb = (u16*)(ws + (512 << 10));                   // 2 MB
    u16* kb = (u16*)(ws + (512 << 10) + (2 << 20));       // 2 MB
    u16* vT = (u16*)(ws + (512 << 10) + (4 << 20));       // 2 MB
    float* Op = (float*)(ws + (8 << 20));                 // 1024*4096*4 = 16.8 MB
    float* Lp = (float*)(ws + (25 << 20));                // 1024*64*4 = 256 KB

    wt_pack<<<1024, 192, 0, stream>>>(Wq, Wk, Wv, Wtt);
    qkv_gemm<<<512, 256, 0, stream>>>(x, Wtt, qb, kb, vT);
    attn_part<<<640, 256, 0, stream>>>(qb, kb, vT, Op, Lp);
    attn_combine<<<4096, 256, 0, stream>>>(Op, Lp, out);
}